// Round 1
// baseline (452.392 us; speedup 1.0000x reference)
//
#include <hip/hip_runtime.h>

#define NTOK 4096          // B*N
#define AST  264           // LDS A-tile row stride in shorts (bank-conflict pad)

using short8  = __attribute__((ext_vector_type(8))) short;
using short4v = __attribute__((ext_vector_type(4))) short;
using floatx4 = __attribute__((ext_vector_type(4))) float;

static __device__ __forceinline__ short f2bf(float f) {
  union { float f; unsigned u; } v; v.f = f;
  unsigned u = v.u;
  u = (u + 0x7fffu + ((u >> 16) & 1u)) >> 16;   // RNE truncate to bf16
  return (short)u;
}

// Pre-swizzle W1[0:256,0:256] (row-major [k][n] fp32) into bf16 B-fragment order:
// W1s[((s*16 + t)*64 + lane)*8 + j] = bf16(W1[(s*32 + (lane>>4)*8 + j)*256 + t*16 + (lane&15)])
// so the main kernel's B loads are one coalesced 16B load per lane.
__global__ void prep_w1(const float* __restrict__ W1, short* __restrict__ W1s) {
  int T = blockIdx.x * 256 + threadIdx.x;   // 0..65535
  int j = T & 7;
  int l = (T >> 3) & 63;
  int t = (T >> 9) & 15;
  int s = T >> 13;
  int k = s * 32 + (l >> 4) * 8 + j;
  int n = t * 16 + (l & 15);
  W1s[T] = f2bf(W1[k * 256 + n]);
}

__global__ void __launch_bounds__(256) agg_kernel(
    const float* __restrict__ sampled, const float* __restrict__ valid,
    const float* __restrict__ y_norm, const float* __restrict__ W1,
    const float* __restrict__ b1, const float* __restrict__ W2,
    const float* __restrict__ b2, const short* __restrict__ W1s,
    float* __restrict__ out) {
  __shared__ __align__(16) short Abf[64 * AST];   // 33,792 B bf16 A tile
  __shared__ float wlog[4][64];                   // per-wave partial logits
  __shared__ float wts[64];                       // final softmax weights
  __shared__ float ynl[64];                       // y_norm

  const int tid = threadIdx.x;
  const int tok = blockIdx.x;
  const float* S = sampled + ((size_t)tok << 14);   // 64*256 floats per token

  // ---- phase 0: stage sampled tile to LDS as bf16 ----
  if (tid < 64) ynl[tid] = y_norm[tid];
  #pragma unroll
  for (int it = 0; it < 16; ++it) {
    int j  = it * 256 + tid;        // float4 index 0..4095
    int y  = j >> 6;                // 64 float4 per row
    int k4 = (j & 63) << 2;
    float4 v = ((const float4*)S)[j];
    short4v p;
    p[0] = f2bf(v.x); p[1] = f2bf(v.y); p[2] = f2bf(v.z); p[3] = f2bf(v.w);
    *(short4v*)(&Abf[y * AST + k4]) = p;
  }
  __syncthreads();

  // ---- phase 1: GEMM  z[64x256] = A(bf16) * W1[0:256](bf16), fp32 acc ----
  const int wv  = tid >> 6;        // wave 0..3 -> owns n in [64*wv, 64*wv+64)
  const int ln  = tid & 63;
  const int q   = ln >> 4;
  const int c15 = ln & 15;

  const floatx4 fzero = {0.f, 0.f, 0.f, 0.f};
  floatx4 acc[4][4];
  #pragma unroll
  for (int mt = 0; mt < 4; ++mt)
    #pragma unroll
    for (int nt = 0; nt < 4; ++nt) acc[mt][nt] = fzero;

  #pragma unroll
  for (int s = 0; s < 8; ++s) {
    short8 af[4];
    #pragma unroll
    for (int mt = 0; mt < 4; ++mt)
      af[mt] = *(const short8*)(&Abf[(mt * 16 + c15) * AST + s * 32 + q * 8]);
    #pragma unroll
    for (int nt = 0; nt < 4; ++nt) {
      const int t = wv * 4 + nt;
      short8 bfrag = *(const short8*)(W1s + (((s * 16 + t) * 64 + ln) << 3));
      #pragma unroll
      for (int mt = 0; mt < 4; ++mt)
        acc[mt][nt] = __builtin_amdgcn_mfma_f32_16x16x32_bf16(af[mt], bfrag, acc[mt][nt], 0, 0, 0);
    }
  }

  // ---- phase 2: epilogue  h = gelu(z + y*W1_last + b1); partial logits = h.W2 ----
  float w2v[4], b1v[4], wlv[4];
  #pragma unroll
  for (int nt = 0; nt < 4; ++nt) {
    int n = wv * 64 + nt * 16 + c15;
    w2v[nt] = W2[n];
    b1v[nt] = b1[n];
    wlv[nt] = W1[65536 + n];        // W1[256][n] — the y-feature row
  }
  #pragma unroll
  for (int mt = 0; mt < 4; ++mt) {
    #pragma unroll
    for (int r = 0; r < 4; ++r) {
      int m = mt * 16 + q * 4 + r;    // D row = quad*4 + reg
      float ym = ynl[m];
      float p = 0.f;
      #pragma unroll
      for (int nt = 0; nt < 4; ++nt) {
        float z = acc[mt][nt][r] + ym * wlv[nt] + b1v[nt];
        float h = 0.5f * z * (1.0f + erff(z * 0.70710678118654752f));  // exact gelu
        p += h * w2v[nt];
      }
      // reduce over the 16 cols held by lanes c15=0..15
      p += __shfl_xor(p, 1);
      p += __shfl_xor(p, 2);
      p += __shfl_xor(p, 4);
      p += __shfl_xor(p, 8);
      if (c15 == 0) wlog[wv][m] = p;
    }
  }
  __syncthreads();

  // ---- phase 3: masked softmax over Y=64 (wave 0) ----
  if (tid < 64) {
    float lg = wlog[0][tid] + wlog[1][tid] + wlog[2][tid] + wlog[3][tid] + b2[0];
    float v  = valid[tok * 64 + tid];
    float lm = (v < 0.5f) ? -10000.0f : lg;
    float mx = lm;
    #pragma unroll
    for (int d = 32; d > 0; d >>= 1) mx = fmaxf(mx, __shfl_xor(mx, d));
    float e  = expf(lm - mx);
    float s1 = e;
    #pragma unroll
    for (int d = 32; d > 0; d >>= 1) s1 += __shfl_xor(s1, d);
    float wgt = e / s1 * v;
    float s2  = wgt;
    #pragma unroll
    for (int d = 32; d > 0; d >>= 1) s2 += __shfl_xor(s2, d);
    wts[tid] = wgt / fmaxf(s2, 1e-6f);
  }
  __syncthreads();

  // ---- phase 4: out[c] = sum_y sampled[y][c] * w[y]  (fp32, L2-hot re-read) ----
  float a0 = 0.f;
  #pragma unroll 8
  for (int y = 0; y < 64; ++y)
    a0 = fmaf(S[(y << 8) + tid], wts[y], a0);
  out[(size_t)tok * 256 + tid] = a0;
}

extern "C" void kernel_launch(void* const* d_in, const int* in_sizes, int n_in,
                              void* d_out, int out_size, void* d_ws, size_t ws_size,
                              hipStream_t stream) {
  const float* sampled = (const float*)d_in[0];
  const float* valid   = (const float*)d_in[1];
  const float* y_norm  = (const float*)d_in[2];
  const float* W1      = (const float*)d_in[3];   // [257,256]
  const float* b1      = (const float*)d_in[4];
  const float* W2      = (const float*)d_in[5];
  const float* b2      = (const float*)d_in[6];
  short* W1s = (short*)d_ws;                      // 128 KiB swizzled bf16 W1
  float* out = (float*)d_out;

  prep_w1<<<256, 256, 0, stream>>>(W1, W1s);
  agg_kernel<<<NTOK, 256, 0, stream>>>(sampled, valid, y_norm, W1, b1, W2, b2, W1s, out);
}

// Round 2
// 411.539 us; speedup vs baseline: 1.0993x; 1.0993x over previous
//
#include <hip/hip_runtime.h>

#define NTOK 4096          // B*N
#define AST  264           // LDS A-tile row stride in shorts (bank-conflict pad)

using short8  = __attribute__((ext_vector_type(8))) short;
using short4v = __attribute__((ext_vector_type(4))) short;
using floatx4 = __attribute__((ext_vector_type(4))) float;

static __device__ __forceinline__ short f2bf(float f) {
  union { float f; unsigned u; } v; v.f = f;
  unsigned u = v.u;
  u = (u + 0x7fffu + ((u >> 16) & 1u)) >> 16;   // RNE truncate to bf16
  return (short)u;
}

static __device__ __forceinline__ float bf2f(short s) {
  union { unsigned u; float f; } v; v.u = ((unsigned)(unsigned short)s) << 16;
  return v.f;
}

// Branchless exact-enough GELU: erf via Abramowitz-Stegun 7.1.26 (|eps|<=1.5e-7).
// ~15 VALU instrs vs ~100 for libm erff.
static __device__ __forceinline__ float fast_gelu(float z) {
  float x  = z * 0.70710678118654752f;
  float ax = fabsf(x);
  float t  = __builtin_amdgcn_rcpf(fmaf(0.3275911f, ax, 1.0f));
  float em = __expf(-ax * ax);
  float p  = fmaf(fmaf(fmaf(fmaf(1.061405429f, t, -1.453152027f), t,
                            1.421413741f), t, -0.284496736f), t, 0.254829592f);
  float er = fmaf(-p * t, em, 1.0f);                 // erf(|x|) in [0,1)
  unsigned sgn = __float_as_uint(x) & 0x80000000u;
  er = __uint_as_float(__float_as_uint(er) | sgn);   // copysign
  return z * fmaf(0.5f, er, 0.5f);
}

// Coalesced pre-swizzle of W1[0:256,0:256] into bf16 B-fragment order:
// W1s[((s*16 + t)*64 + l)*8 + j] = bf16(W1[k*256 + n]),
//   k = s*32 + (l>>4)*8 + j, n = t*16 + (l&15).
// Block kb handles k rows 8kb..8kb+7; thread = n. Reads wave-coalesced per j,
// one short8 (16B) store per thread.
__global__ void prep_w1(const float* __restrict__ W1, short* __restrict__ W1s) {
  const int n  = threadIdx.x;     // 0..255
  const int kb = blockIdx.x;      // 0..31
  const int s  = kb >> 2;
  const int l  = ((kb & 3) << 4) | (n & 15);
  const int t  = n >> 4;
  short8 o;
  #pragma unroll
  for (int j = 0; j < 8; ++j)
    o[j] = f2bf(W1[(kb * 8 + j) * 256 + n]);
  *(short8*)(W1s + (((s * 16 + t) * 64 + l) << 3)) = o;
}

__global__ void __launch_bounds__(256, 4) agg_kernel(
    const float* __restrict__ sampled, const float* __restrict__ valid,
    const float* __restrict__ y_norm, const float* __restrict__ W1,
    const float* __restrict__ b1, const float* __restrict__ W2,
    const float* __restrict__ b2, const short* __restrict__ W1s,
    float* __restrict__ out) {
  __shared__ __align__(16) short Abf[64 * AST];   // 33,792 B bf16 A tile
  __shared__ float wlog[4][64];                   // per-wave partial logits
  __shared__ float ynl[64];                       // y_norm

  const int tid = threadIdx.x;
  const int tok = blockIdx.x;
  const float* S = sampled + ((size_t)tok << 14);   // 64*256 floats per token

  // ---- phase 0: stage sampled tile to LDS as bf16 (8-deep load pipeline) ----
  if (tid < 64) ynl[tid] = y_norm[tid];
  const float4* S4 = (const float4*)S;
  #pragma unroll
  for (int h = 0; h < 2; ++h) {
    float4 v[8];
    #pragma unroll
    for (int it = 0; it < 8; ++it) v[it] = S4[(h * 8 + it) * 256 + tid];
    #pragma unroll
    for (int it = 0; it < 8; ++it) {
      int j  = (h * 8 + it) * 256 + tid;
      int y  = j >> 6;
      int k4 = (j & 63) << 2;
      short4v p;
      p[0] = f2bf(v[it].x); p[1] = f2bf(v[it].y);
      p[2] = f2bf(v[it].z); p[3] = f2bf(v[it].w);
      *(short4v*)(&Abf[y * AST + k4]) = p;
    }
  }
  __syncthreads();

  // ---- phase 1: GEMM  z[64x256] = A(bf16) * W1[0:256](bf16), fp32 acc ----
  const int wv  = tid >> 6;        // wave 0..3 -> owns n in [64*wv, 64*wv+64)
  const int ln  = tid & 63;
  const int q   = ln >> 4;
  const int c15 = ln & 15;

  const floatx4 fzero = {0.f, 0.f, 0.f, 0.f};
  floatx4 acc[4][4];
  #pragma unroll
  for (int mt = 0; mt < 4; ++mt)
    #pragma unroll
    for (int nt = 0; nt < 4; ++nt) acc[mt][nt] = fzero;

  #pragma unroll
  for (int s = 0; s < 8; ++s) {
    short8 af[4];
    #pragma unroll
    for (int mt = 0; mt < 4; ++mt)
      af[mt] = *(const short8*)(&Abf[(mt * 16 + c15) * AST + s * 32 + q * 8]);
    #pragma unroll
    for (int nt = 0; nt < 4; ++nt) {
      const int t = wv * 4 + nt;
      short8 bfrag = *(const short8*)(W1s + (((s * 16 + t) * 64 + ln) << 3));
      #pragma unroll
      for (int mt = 0; mt < 4; ++mt)
        acc[mt][nt] = __builtin_amdgcn_mfma_f32_16x16x32_bf16(af[mt], bfrag, acc[mt][nt], 0, 0, 0);
    }
  }

  // ---- phase 2: epilogue  h = gelu(z + y*W1_last + b1); partial logits = h.W2 ----
  float w2v[4], b1v[4], wlv[4];
  #pragma unroll
  for (int nt = 0; nt < 4; ++nt) {
    int n = wv * 64 + nt * 16 + c15;
    w2v[nt] = W2[n];
    b1v[nt] = b1[n];
    wlv[nt] = W1[65536 + n];        // W1[256][n] — the y-feature row
  }
  #pragma unroll
  for (int mt = 0; mt < 4; ++mt) {
    #pragma unroll
    for (int r = 0; r < 4; ++r) {
      int m = mt * 16 + q * 4 + r;    // D row = quad*4 + reg
      float ym = ynl[m];
      float p = 0.f;
      #pragma unroll
      for (int nt = 0; nt < 4; ++nt) {
        float z = acc[mt][nt][r] + ym * wlv[nt] + b1v[nt];
        p += fast_gelu(z) * w2v[nt];
      }
      // reduce over the 16 cols held by lanes c15=0..15
      p += __shfl_xor(p, 1);
      p += __shfl_xor(p, 2);
      p += __shfl_xor(p, 4);
      p += __shfl_xor(p, 8);
      if (c15 == 0) wlog[wv][m] = p;
    }
  }
  __syncthreads();

  // ---- phase 3: masked softmax over Y=64, redundantly in every wave ----
  float lg = wlog[0][ln] + wlog[1][ln] + wlog[2][ln] + wlog[3][ln] + b2[0];
  float vv = valid[tok * 64 + ln];
  float lm = (vv < 0.5f) ? -10000.0f : lg;
  float mx = lm;
  #pragma unroll
  for (int d = 32; d > 0; d >>= 1) mx = fmaxf(mx, __shfl_xor(mx, d));
  float e  = __expf(lm - mx);
  float s1 = e;
  #pragma unroll
  for (int d = 32; d > 0; d >>= 1) s1 += __shfl_xor(s1, d);
  float wgt = e / s1 * vv;
  float s2  = wgt;
  #pragma unroll
  for (int d = 32; d > 0; d >>= 1) s2 += __shfl_xor(s2, d);
  wgt = wgt / fmaxf(s2, 1e-6f);     // lane ln holds weight for y=ln

  // ---- phase 4: out[c] = sum_y A_bf16[y][c] * w[y]  (LDS reads, no barrier) ----
  float a0 = 0.f;
  #pragma unroll
  for (int y = 0; y < 64; ++y) {
    float wy = __shfl(wgt, y);      // compile-time lane -> v_readlane (SGPR)
    a0 = fmaf(bf2f(Abf[y * AST + tid]), wy, a0);
  }
  out[(size_t)tok * 256 + tid] = a0;
}

extern "C" void kernel_launch(void* const* d_in, const int* in_sizes, int n_in,
                              void* d_out, int out_size, void* d_ws, size_t ws_size,
                              hipStream_t stream) {
  const float* sampled = (const float*)d_in[0];
  const float* valid   = (const float*)d_in[1];
  const float* y_norm  = (const float*)d_in[2];
  const float* W1      = (const float*)d_in[3];   // [257,256]
  const float* b1      = (const float*)d_in[4];
  const float* W2      = (const float*)d_in[5];
  const float* b2      = (const float*)d_in[6];
  short* W1s = (short*)d_ws;                      // 128 KiB swizzled bf16 W1
  float* out = (float*)d_out;

  prep_w1<<<32, 256, 0, stream>>>(W1, W1s);
  agg_kernel<<<NTOK, 256, 0, stream>>>(sampled, valid, y_norm, W1, b1, W2, b2, W1s, out);
}